// Round 6
// baseline (2074.202 us; speedup 1.0000x reference)
//
#include <hip/hip_runtime.h>

#define H_DIM 128
#define F_IN  384
#define W1_STRIDE 388   // +4 elem pad: row start banks spread (row*194%32), ~2-way max
#define HS_STRIDE 136   // proven r0 geometry (row stride 272B)
#define NWAVE 12        // 768 threads, 12 waves, 1 block/CU, 3 waves/SIMD
#define TILE_E (NWAVE * 16)   // 192 edges per tile

typedef __bf16 v8bf __attribute__((ext_vector_type(8)));
typedef float  v4f  __attribute__((ext_vector_type(4)));

// order-preserving float <-> uint encoding for atomicMax
__device__ __forceinline__ unsigned enc_f32(float v) {
    unsigned u = __float_as_uint(v);
    return (u & 0x80000000u) ? ~u : (u | 0x80000000u);
}
__device__ __forceinline__ float dec_f32(unsigned e) {
    if (e == 0u) return 0.0f;  // untouched node -> 0 (matches reference where())
    unsigned u = (e & 0x80000000u) ? (e & 0x7fffffffu) : ~e;
    return __uint_as_float(u);
}

// W1 [F_IN][H] fp32 -> W1T [H][F_IN] bf16 ; W2 [H][H] fp32 -> W2T [H][H] bf16
__global__ __launch_bounds__(256) void wconvert(const float* __restrict__ W1,
                                                const float* __restrict__ W2,
                                                __bf16* __restrict__ W1T,
                                                __bf16* __restrict__ W2T) {
    int i = blockIdx.x * 256 + threadIdx.x;
    if (i < F_IN * H_DIM) {
        int col = i / F_IN, k = i % F_IN;
        W1T[i] = (__bf16)W1[k * H_DIM + col];
    } else if (i < F_IN * H_DIM + H_DIM * H_DIM) {
        int j = i - F_IN * H_DIM;
        int col = j / H_DIM, k = j % H_DIM;
        W2T[j] = (__bf16)W2[k * H_DIM + col];
    }
}

// Persistent: grid=256 (1 block/CU), 768 threads = 12 waves (3/SIMD).
// W1T staged to LDS ONCE (one barrier per block lifetime); grid-stride over
// 192-edge tiles with ZERO barriers in the loop. Leaf prefetch is the shallow
// r0 pattern (1 k-step ahead) -> bounded in-flight, no L2 overflow/double-fetch.
__global__ __launch_bounds__(768, 3) void mlp_scatter(
    const float* __restrict__ leaf, const int* __restrict__ nidx,
    const __bf16* __restrict__ W1T, const __bf16* __restrict__ W2T,
    const float* __restrict__ b1, const float* __restrict__ b2,
    unsigned* __restrict__ agg, int E, int ntiles)
{
    __shared__ __bf16 w1s[128][W1_STRIDE];        // 99,328 B, resident all kernel
    __shared__ __bf16 hs[NWAVE][16][HS_STRIDE];   // 52,224 B, wave-private

    const int t  = threadIdx.x;
    const int w  = t >> 6;    // wave 0..11
    const int l  = t & 63;
    const int lr = l & 15;    // row/col within fragment
    const int lg = l >> 4;    // k-group

    // ---- stage W1T (96KB) into LDS once: thread t -> row t/6, 64-col segment t%6 ----
    {
        const int row = t / 6;          // 0..127 (767/6 = 127)
        const int seg = t % 6;          // 0..5
        const __bf16* src = W1T + row * F_IN + seg * 64;
#pragma unroll
        for (int i = 0; i < 8; ++i)
            *(v8bf*)&w1s[row][seg * 64 + i * 8] = *(const v8bf*)(src + i * 8);
    }
    // per-lane biases in registers (L1-broadcast loads)
    float bb1[8], bb2[8];
#pragma unroll
    for (int f = 0; f < 8; ++f) { bb1[f] = b1[f * 16 + lr]; bb2[f] = b2[f * 16 + lr]; }
    __syncthreads();   // the only barrier in the kernel

    const int rb = w * 16 + lg * 4;
    const v4f vzero = {0.f, 0.f, 0.f, 0.f};

    for (int tile = blockIdx.x; tile < ntiles; tile += gridDim.x) {
        const long e0 = (long)tile * TILE_E;
        long erow = e0 + w * 16 + lr;
        if (erow >= E) erow = E - 1;          // clamp; epilogue masks fake rows
        const float* arow = leaf + erow * (long)F_IN + lg * 8;

        int nd[4];
#pragma unroll
        for (int j = 0; j < 4; ++j) {
            const long ej = e0 + rb + j;
            nd[j] = (ej < E) ? nidx[ej] : -1;
        }

        // ---- layer 1: h = x @ W1, K=384 in 12 steps; B-frags from resident LDS ----
        v4f acc[8];
#pragma unroll
        for (int f = 0; f < 8; ++f) acc[f] = vzero;

        float4 a0 = *(const float4*)(arow);
        float4 a1 = *(const float4*)(arow + 4);
#pragma unroll
        for (int ks = 0; ks < 12; ++ks) {
            float4 n0, n1;
            if (ks + 1 < 12) {
                n0 = *(const float4*)(arow + (ks + 1) * 32);
                n1 = *(const float4*)(arow + (ks + 1) * 32 + 4);
            }
            v8bf af;
            af[0] = (__bf16)a0.x; af[1] = (__bf16)a0.y;
            af[2] = (__bf16)a0.z; af[3] = (__bf16)a0.w;
            af[4] = (__bf16)a1.x; af[5] = (__bf16)a1.y;
            af[6] = (__bf16)a1.z; af[7] = (__bf16)a1.w;
#pragma unroll
            for (int f = 0; f < 8; ++f) {
                v8bf bfv = *(const v8bf*)&w1s[f * 16 + lr][ks * 32 + lg * 8];
                acc[f] = __builtin_amdgcn_mfma_f32_16x16x32_bf16(af, bfv, acc[f], 0, 0, 0);
            }
            if (ks + 1 < 12) { a0 = n0; a1 = n1; }
        }

        // ---- relu + bias -> bf16 hidden in wave-private LDS ----
#pragma unroll
        for (int f = 0; f < 8; ++f) {
#pragma unroll
            for (int j = 0; j < 4; ++j) {
                float v = fmaxf(acc[f][j] + bb1[f], 0.0f);
                hs[w][lg * 4 + j][f * 16 + lr] = (__bf16)v;
            }
        }

        // ---- layer 2: m = h @ W2, K=128; W2T frags from L1/L2 ----
        v4f acc2[8];
#pragma unroll
        for (int f = 0; f < 8; ++f) acc2[f] = vzero;
#pragma unroll
        for (int ks = 0; ks < 4; ++ks) {
            v8bf af2 = *(const v8bf*)&hs[w][lr][ks * 32 + lg * 8];
#pragma unroll
            for (int f = 0; f < 8; ++f) {
                v8bf bfv = *(const v8bf*)(W2T + (f * 16 + lr) * H_DIM + ks * 32 + lg * 8);
                acc2[f] = __builtin_amdgcn_mfma_f32_16x16x32_bf16(af2, bfv, acc2[f], 0, 0, 0);
            }
        }

        // ---- epilogue: + b2, fire-and-forget scatter-max ----
#pragma unroll
        for (int j = 0; j < 4; ++j) {
            if (nd[j] >= 0) {
                unsigned* dst = agg + (long)nd[j] * H_DIM + lr;
#pragma unroll
                for (int f = 0; f < 8; ++f)
                    atomicMax(dst + f * 16, enc_f32(acc2[f][j] + bb2[f]));
            }
        }
    }
}

// one wave per node row: lang = center + dec(agg); out = cos(gcn, lang)
__global__ __launch_bounds__(256) void cos_kernel(
    const float* __restrict__ center, const float* __restrict__ gcn,
    const unsigned* __restrict__ agg, float* __restrict__ out, int N)
{
    const int w = threadIdx.x >> 6, l = threadIdx.x & 63;
    const long row = (long)blockIdx.x * 4 + w;
    if (row >= N) return;
    const float2 g2 = *(const float2*)(gcn    + row * H_DIM + l * 2);
    const float2 c2 = *(const float2*)(center + row * H_DIM + l * 2);
    const uint2  e2 = *(const uint2*) (agg    + row * H_DIM + l * 2);
    const float l0 = c2.x + dec_f32(e2.x);
    const float l1 = c2.y + dec_f32(e2.y);
    float sgl = g2.x * l0 + g2.y * l1;
    float sgg = g2.x * g2.x + g2.y * g2.y;
    float sll = l0 * l0 + l1 * l1;
#pragma unroll
    for (int off = 32; off; off >>= 1) {
        sgl += __shfl_xor(sgl, off);
        sgg += __shfl_xor(sgg, off);
        sll += __shfl_xor(sll, off);
    }
    if (l == 0) {
        const float na = fmaxf(sqrtf(sgg), 1e-8f);
        const float nb = fmaxf(sqrtf(sll), 1e-8f);
        out[row] = sgl / (na * nb);
    }
}

extern "C" void kernel_launch(void* const* d_in, const int* in_sizes, int n_in,
                              void* d_out, int out_size, void* d_ws, size_t ws_size,
                              hipStream_t stream) {
    const float* center = (const float*)d_in[0];
    const float* leaf   = (const float*)d_in[1];
    const int*   nidx   = (const int*)  d_in[2];
    const float* gcn    = (const float*)d_in[3];
    const float* W1     = (const float*)d_in[4];
    const float* b1     = (const float*)d_in[5];
    const float* W2     = (const float*)d_in[6];
    const float* b2     = (const float*)d_in[7];

    const int E = in_sizes[2];             // 1,000,000
    const int N = in_sizes[0] / H_DIM;     // 65,536

    unsigned* agg = (unsigned*)d_ws;
    const size_t aggBytes = (size_t)N * H_DIM * sizeof(unsigned);
    __bf16* W1T = (__bf16*)((char*)d_ws + aggBytes);
    __bf16* W2T = W1T + (size_t)F_IN * H_DIM;

    const int ntiles = (E + TILE_E - 1) / TILE_E;

    hipMemsetAsync(agg, 0, aggBytes, stream);
    wconvert<<<(F_IN * H_DIM + H_DIM * H_DIM + 255) / 256, 256, 0, stream>>>(W1, W2, W1T, W2T);
    mlp_scatter<<<256, 768, 0, stream>>>(leaf, nidx, W1T, W2T, b1, b2, agg, E, ntiles);
    cos_kernel<<<(N + 3) / 4, 256, 0, stream>>>(center, gcn, agg, (float*)d_out, N);
}

// Round 7
// 716.727 us; speedup vs baseline: 2.8940x; 2.8940x over previous
//
#include <hip/hip_runtime.h>

#define H_DIM 128
#define F_IN  384

typedef __bf16 v8bf __attribute__((ext_vector_type(8)));
typedef float  v4f  __attribute__((ext_vector_type(4)));

// order-preserving float <-> uint encoding for atomicMax
__device__ __forceinline__ unsigned enc_f32(float v) {
    unsigned u = __float_as_uint(v);
    return (u & 0x80000000u) ? ~u : (u | 0x80000000u);
}
__device__ __forceinline__ float dec_f32(unsigned e) {
    if (e == 0u) return 0.0f;  // untouched node -> 0 (matches reference where())
    unsigned u = (e & 0x80000000u) ? (e & 0x7fffffffu) : ~e;
    return __uint_as_float(u);
}

// W1 [F_IN][H] fp32 -> W1T [H][F_IN] bf16 ; W2 [H][H] fp32 -> W2T [H][H] bf16
__global__ __launch_bounds__(256) void wconvert(const float* __restrict__ W1,
                                                const float* __restrict__ W2,
                                                __bf16* __restrict__ W1T,
                                                __bf16* __restrict__ W2T) {
    int i = blockIdx.x * 256 + threadIdx.x;
    if (i < F_IN * H_DIM) {
        int col = i / F_IN, k = i % F_IN;
        W1T[i] = (__bf16)W1[k * H_DIM + col];
    } else if (i < F_IN * H_DIM + H_DIM * H_DIM) {
        int j = i - F_IN * H_DIM;
        int col = j / H_DIM, k = j % H_DIM;
        W2T[j] = (__bf16)W2[k * H_DIM + col];
    }
}

// 64 edges per block, 256 threads (4 waves). Wave w: rows 16w..16w+15, all 128 cols.
// r0 structure (proven 739us) + 4-deep rolling leaf prefetch: one HBM-latency
// drain at the per-step barrier now covers 4 k-steps of A-operands (Little's law:
// ~8KB/wave in flight vs r0's ~2KB).
__global__ __launch_bounds__(256, 4) void mlp_scatter(
    const float* __restrict__ leaf, const int* __restrict__ nidx,
    const __bf16* __restrict__ W1T, const __bf16* __restrict__ W2T,
    const float* __restrict__ b1, const float* __restrict__ b2,
    unsigned* __restrict__ agg, int E)
{
    __shared__ __bf16 wb[2][128][40];   // W1T k-chunk double buffer (pad 40 -> 2-way max)
    __shared__ __bf16 hs[64][136];      // relu hidden, bf16 (pad 136 -> 2-way max)
    __shared__ int   idx_s[64];
    __shared__ float b1_s[H_DIM], b2_s[H_DIM];

    const int t  = threadIdx.x;
    const int w  = t >> 6;
    const int l  = t & 63;
    const int lr = l & 15;   // row/col within fragment
    const int lg = l >> 4;   // k-group
    const long e0 = (long)blockIdx.x * 64;

    if (t < 64) {
        long e = e0 + t;
        idx_s[t] = nidx[e < E ? e : (E - 1)];
    }
    if (t < H_DIM) { b1_s[t] = b1[t]; b2_s[t] = b2[t]; }

    // stage W1T chunk ks=0 into buffer 0 (each thread: 32B of one column)
    {
        const int col = t >> 1, kh = (t & 1) * 16;
        const v8bf* src = (const v8bf*)(W1T + col * F_IN + kh);
        *(v8bf*)&wb[0][col][kh]     = src[0];
        *(v8bf*)&wb[0][col][kh + 8] = src[1];
    }

    long erow = e0 + w * 16 + lr;
    if (erow >= E) erow = E - 1;          // clamp (tail-safe; epilogue masks)
    const float* arow = leaf + erow * (long)F_IN + lg * 8;

    const v4f vzero = {0.f, 0.f, 0.f, 0.f};
    v4f acc[8];
#pragma unroll
    for (int f = 0; f < 8; ++f) acc[f] = vzero;

    // 4-deep rolling prefetch of leaf A-operands
    float4 A0[4], A1[4];
#pragma unroll
    for (int p = 0; p < 4; ++p) {
        A0[p] = *(const float4*)(arow + p * 32);
        A1[p] = *(const float4*)(arow + p * 32 + 4);
    }
    __syncthreads();

    // ---- layer 1: h = x @ W1, K=384 in 12 steps of 32 ----
#pragma unroll
    for (int ks = 0; ks < 12; ++ks) {
        // stage next W1T chunk (L2/L3 hits) into the other buffer
        if (ks + 1 < 12) {
            const int col = t >> 1, kh = (t & 1) * 16;
            const v8bf* src = (const v8bf*)(W1T + col * F_IN + (ks + 1) * 32 + kh);
            const int b = (ks + 1) & 1;
            *(v8bf*)&wb[b][col][kh]     = src[0];
            *(v8bf*)&wb[b][col][kh + 8] = src[1];
        }
        // consume slot ks&3, then refill it with ks+4 (issued before MFMAs)
        v8bf af;
        af[0] = (__bf16)A0[ks & 3].x; af[1] = (__bf16)A0[ks & 3].y;
        af[2] = (__bf16)A0[ks & 3].z; af[3] = (__bf16)A0[ks & 3].w;
        af[4] = (__bf16)A1[ks & 3].x; af[5] = (__bf16)A1[ks & 3].y;
        af[6] = (__bf16)A1[ks & 3].z; af[7] = (__bf16)A1[ks & 3].w;
        if (ks + 4 < 12) {
            A0[ks & 3] = *(const float4*)(arow + (ks + 4) * 32);
            A1[ks & 3] = *(const float4*)(arow + (ks + 4) * 32 + 4);
        }
        const int cb = ks & 1;
#pragma unroll
        for (int f = 0; f < 8; ++f) {
            v8bf bfv = *(const v8bf*)&wb[cb][f * 16 + lr][lg * 8];
            acc[f] = __builtin_amdgcn_mfma_f32_16x16x32_bf16(af, bfv, acc[f], 0, 0, 0);
        }
        __syncthreads();
    }

    // ---- relu + bias -> bf16 hidden in LDS ----
#pragma unroll
    for (int f = 0; f < 8; ++f) {
        const float bb = b1_s[f * 16 + lr];
#pragma unroll
        for (int j = 0; j < 4; ++j) {
            float v = acc[f][j] + bb;
            v = fmaxf(v, 0.0f);
            hs[w * 16 + lg * 4 + j][f * 16 + lr] = (__bf16)v;
        }
    }
    __syncthreads();

    // ---- layer 2: m = h @ W2, K=128 in 4 steps; W2T frags from L1/L2 ----
    v4f acc2[8];
#pragma unroll
    for (int f = 0; f < 8; ++f) acc2[f] = vzero;
#pragma unroll
    for (int ks = 0; ks < 4; ++ks) {
        v8bf af2 = *(const v8bf*)&hs[w * 16 + lr][ks * 32 + lg * 8];
#pragma unroll
        for (int f = 0; f < 8; ++f) {
            v8bf bfv = *(const v8bf*)(W2T + (f * 16 + lr) * H_DIM + ks * 32 + lg * 8);
            acc2[f] = __builtin_amdgcn_mfma_f32_16x16x32_bf16(af2, bfv, acc2[f], 0, 0, 0);
        }
    }

    // ---- epilogue: + b2, encode, scatter-max ----
    const int rb = w * 16 + lg * 4;
#pragma unroll
    for (int j = 0; j < 4; ++j) {
        const long ej = e0 + rb + j;
        if (ej < E) {
            const int node = idx_s[rb + j];
            unsigned* dst = agg + (long)node * H_DIM + lr;
#pragma unroll
            for (int f = 0; f < 8; ++f) {
                float v = acc2[f][j] + b2_s[f * 16 + lr];
                atomicMax(dst + f * 16, enc_f32(v));
            }
        }
    }
}

// one wave per node row: lang = center + dec(agg); out = cos(gcn, lang)
__global__ __launch_bounds__(256) void cos_kernel(
    const float* __restrict__ center, const float* __restrict__ gcn,
    const unsigned* __restrict__ agg, float* __restrict__ out, int N)
{
    const int w = threadIdx.x >> 6, l = threadIdx.x & 63;
    const long row = (long)blockIdx.x * 4 + w;
    if (row >= N) return;
    const float2 g2 = *(const float2*)(gcn    + row * H_DIM + l * 2);
    const float2 c2 = *(const float2*)(center + row * H_DIM + l * 2);
    const uint2  e2 = *(const uint2*) (agg    + row * H_DIM + l * 2);
    const float l0 = c2.x + dec_f32(e2.x);
    const float l1 = c2.y + dec_f32(e2.y);
    float sgl = g2.x * l0 + g2.y * l1;
    float sgg = g2.x * g2.x + g2.y * g2.y;
    float sll = l0 * l0 + l1 * l1;
#pragma unroll
    for (int off = 32; off; off >>= 1) {
        sgl += __shfl_xor(sgl, off);
        sgg += __shfl_xor(sgg, off);
        sll += __shfl_xor(sll, off);
    }
    if (l == 0) {
        const float na = fmaxf(sqrtf(sgg), 1e-8f);
        const float nb = fmaxf(sqrtf(sll), 1e-8f);
        out[row] = sgl / (na * nb);
    }
}

extern "C" void kernel_launch(void* const* d_in, const int* in_sizes, int n_in,
                              void* d_out, int out_size, void* d_ws, size_t ws_size,
                              hipStream_t stream) {
    const float* center = (const float*)d_in[0];
    const float* leaf   = (const float*)d_in[1];
    const int*   nidx   = (const int*)  d_in[2];
    const float* gcn    = (const float*)d_in[3];
    const float* W1     = (const float*)d_in[4];
    const float* b1     = (const float*)d_in[5];
    const float* W2     = (const float*)d_in[6];
    const float* b2     = (const float*)d_in[7];

    const int E = in_sizes[2];             // 1,000,000
    const int N = in_sizes[0] / H_DIM;     // 65,536

    unsigned* agg = (unsigned*)d_ws;
    const size_t aggBytes = (size_t)N * H_DIM * sizeof(unsigned);
    __bf16* W1T = (__bf16*)((char*)d_ws + aggBytes);
    __bf16* W2T = W1T + (size_t)F_IN * H_DIM;

    hipMemsetAsync(agg, 0, aggBytes, stream);
    wconvert<<<(F_IN * H_DIM + H_DIM * H_DIM + 255) / 256, 256, 0, stream>>>(W1, W2, W1T, W2T);
    mlp_scatter<<<(E + 63) / 64, 256, 0, stream>>>(leaf, nidx, W1T, W2T, b1, b2, agg, E);
    cos_kernel<<<(N + 3) / 4, 256, 0, stream>>>(center, gcn, agg, (float*)d_out, N);
}